// Round 19
// baseline (57.438 us; speedup 1.0000x reference)
//
#include <hip/hip_runtime.h>

#define B_ 8
#define N_ 256
#define D_ 512

// ---------- Kernel 0: transpose k[b][j][d] -> kT[b][d][j] (verified R2) ----
__global__ __launch_bounds__(256)
void transpose_k(const float* __restrict__ k, float* __restrict__ kT)
{
    __shared__ float tile[32][33];
    const int dt = blockIdx.x * 32;
    const int jt = blockIdx.y * 32;
    const int b  = blockIdx.z;
    const int tx = threadIdx.x;   // 0..31
    const int ty = threadIdx.y;   // 0..7

    const float* __restrict__ src = k  + ((size_t)b * N_) * D_;
    float* __restrict__       dst = kT + ((size_t)b * D_) * N_;

    #pragma unroll
    for (int r = 0; r < 4; ++r) {
        const int jj = ty * 4 + r;
        tile[jj][tx] = src[(size_t)(jt + jj) * D_ + dt + tx];
    }
    __syncthreads();
    #pragma unroll
    for (int r = 0; r < 4; ++r) {
        const int dd = ty * 4 + r;
        dst[(size_t)(dt + dd) * N_ + jt + tx] = tile[tx][dd];
    }
}

// ================= Kernel A: barrier-free streaming, 32 waves/CU ==========
// grid 1024: b=bid&7, itile=(bid>>3)&31 -> 8 rows, jq=bid>>8 -> 64 j.
// 512 thr: thread = (jq4 = t&15, rh = (t>>4)&7, dh = t>>7 -> 128-d quarter).
// Same traffic/coalescing as R18 scores6 (16-lane 256B kT segments, 4-way
// row-group broadcast; q L1-hot) but 8 waves/block x 4 blocks/CU =
// 32 waves/CU (vs 16) -> halves the latency stall R18 exposed.
// Barrier-free main loop; one 4-way d-quarter reduce at the end.
__global__ __launch_bounds__(512)
void manh_scores7(const float* __restrict__ q,
                  const float* __restrict__ kT,
                  float* __restrict__ S)
{
    __shared__ __align__(16) float s_red[2048];   // 8 KB: [dh][rh][jq4][4]

    const int t     = threadIdx.x;
    const int b     = blockIdx.x & 7;          // batch -> XCD locality
    const int itile = (blockIdx.x >> 3) & 31;
    const int jq    = blockIdx.x >> 8;         // 0..3
    const int ibase = itile * 8;
    const int jbase = jq * 64;

    const int jq4 = t & 15;          // j quad: j = jbase + jq4*4 .. +3
    const int rh  = (t >> 4) & 7;    // row
    const int dh  = t >> 7;          // d-quarter 0..3 (128 d each)

    const float* __restrict__ kcol =
        kT + (size_t)b * D_ * N_ + (size_t)(dh * 128) * N_ + jbase + jq4 * 4;
    const float* __restrict__ qr =
        q + ((size_t)(b * N_ + ibase + rh)) * D_ + dh * 128;

    float4 acc = make_float4(0.f, 0.f, 0.f, 0.f);

    const float* kp = kcol;
    #pragma unroll 2
    for (int dd = 0; dd < 128; dd += 4) {
        const float4 qv = *(const float4*)(qr + dd);
        const float4 k0 = *(const float4*)(kp);
        const float4 k1 = *(const float4*)(kp + N_);
        const float4 k2 = *(const float4*)(kp + 2 * N_);
        const float4 k3 = *(const float4*)(kp + 3 * N_);
        kp += 4 * N_;
        acc.x += (fabsf(qv.x - k0.x) + fabsf(qv.y - k1.x)) +
                 (fabsf(qv.z - k2.x) + fabsf(qv.w - k3.x));
        acc.y += (fabsf(qv.x - k0.y) + fabsf(qv.y - k1.y)) +
                 (fabsf(qv.z - k2.y) + fabsf(qv.w - k3.y));
        acc.z += (fabsf(qv.x - k0.z) + fabsf(qv.y - k1.z)) +
                 (fabsf(qv.z - k2.z) + fabsf(qv.w - k3.z));
        acc.w += (fabsf(qv.x - k0.w) + fabsf(qv.y - k1.w)) +
                 (fabsf(qv.z - k2.w) + fabsf(qv.w - k3.w));
    }

    // ---- reduce 4 d-quarters ----
    // write: wave-contiguous float4 (1KB/wave) -> conflict-free
    *(float4*)&s_red[dh * 512 + (rh * 16 + jq4) * 4] = acc;
    __syncthreads();
    if (t < 128) {
        const int r   = t >> 4;            // 0..7
        const int jj4 = t & 15;
        const float4 p0 = *(const float4*)&s_red[0 * 512 + t * 4];
        const float4 p1 = *(const float4*)&s_red[1 * 512 + t * 4];
        const float4 p2 = *(const float4*)&s_red[2 * 512 + t * 4];
        const float4 p3 = *(const float4*)&s_red[3 * 512 + t * 4];
        float4 o;
        o.x = -((p0.x + p1.x) + (p2.x + p3.x));
        o.y = -((p0.y + p1.y) + (p2.y + p3.y));
        o.z = -((p0.z + p1.z) + (p2.z + p3.z));
        o.w = -((p0.w + p1.w) + (p2.w + p3.w));
        *(float4*)(S + (size_t)b * N_ * N_ + (size_t)(ibase + r) * N_
                     + jbase + jj4 * 4) = o;
    }
}

// ================= Kernel B: softmax(S) @ v, 8 rows/block (verified R13) ===
__global__ __launch_bounds__(512, 4)
void manh_sm_pv8(const float* __restrict__ S,
                 const float* __restrict__ v,
                 float* __restrict__ out)
{
    __shared__ __align__(16) float s_w[8 * N_];      // 8 KB
    __shared__ __align__(16) float s_part[8 * 1024]; // 32 KB

    const int t     = threadIdx.x;
    const int lane  = t & 63;
    const int w     = t >> 6;              // 0..7
    const int b     = blockIdx.x & 7;
    const int itile = (blockIdx.x >> 3) & 31;
    const int dh    = blockIdx.x >> 8;     // 0..1
    const int i0    = itile * 8;

    *(float4*)&s_w[4 * t] =
        *(const float4*)(S + (size_t)b * N_ * N_ + (size_t)i0 * N_ + 4 * t);
    __syncthreads();

    {
        float* row = &s_w[w * N_];
        float v0 = row[lane];
        float v1 = row[lane + 64];
        float v2 = row[lane + 128];
        float v3 = row[lane + 192];
        float m = fmaxf(fmaxf(v0, v1), fmaxf(v2, v3));
        #pragma unroll
        for (int off = 32; off; off >>= 1) m = fmaxf(m, __shfl_xor(m, off));
        const float cc = 1.4426950408889634f;
        float e0 = exp2f((v0 - m) * cc);
        float e1 = exp2f((v1 - m) * cc);
        float e2 = exp2f((v2 - m) * cc);
        float e3 = exp2f((v3 - m) * cc);
        float s = (e0 + e1) + (e2 + e3);
        #pragma unroll
        for (int off = 32; off; off >>= 1) s += __shfl_xor(s, off);
        const float r = 1.0f / s;
        row[lane]       = e0 * r;
        row[lane + 64]  = e1 * r;
        row[lane + 128] = e2 * r;
        row[lane + 192] = e3 * r;
    }
    __syncthreads();

    const int dq    = t & 63;
    const int jh    = t >> 6;              // == wave -> s_w reads wave-uniform
    const int dbase = dh * 256 + dq * 4;
    const float* __restrict__ vb = v + (size_t)b * N_ * D_ + dbase;

    float4 a0 = make_float4(0.f,0.f,0.f,0.f), a1 = a0, a2 = a0, a3 = a0;
    float4 a4 = a0, a5 = a0, a6 = a0, a7 = a0;

#define PVROW(A, W)                                                            \
    A.x += (W).x * vv0.x + (W).y * vv1.x + (W).z * vv2.x + (W).w * vv3.x;      \
    A.y += (W).x * vv0.y + (W).y * vv1.y + (W).z * vv2.y + (W).w * vv3.y;      \
    A.z += (W).x * vv0.z + (W).y * vv1.z + (W).z * vv2.z + (W).w * vv3.z;      \
    A.w += (W).x * vv0.w + (W).y * vv1.w + (W).z * vv2.w + (W).w * vv3.w;

    #pragma unroll 2
    for (int jo = 0; jo < 32; jo += 4) {
        const int jj = jh * 32 + jo;
        const float4 vv0 = *(const float4*)(vb + (size_t)(jj + 0) * D_);
        const float4 vv1 = *(const float4*)(vb + (size_t)(jj + 1) * D_);
        const float4 vv2 = *(const float4*)(vb + (size_t)(jj + 2) * D_);
        const float4 vv3 = *(const float4*)(vb + (size_t)(jj + 3) * D_);
        const float4 w0 = *(const float4*)&s_w[0 * N_ + jj];
        const float4 w1 = *(const float4*)&s_w[1 * N_ + jj];
        const float4 w2 = *(const float4*)&s_w[2 * N_ + jj];
        const float4 w3 = *(const float4*)&s_w[3 * N_ + jj];
        const float4 w4 = *(const float4*)&s_w[4 * N_ + jj];
        const float4 w5 = *(const float4*)&s_w[5 * N_ + jj];
        const float4 w6 = *(const float4*)&s_w[6 * N_ + jj];
        const float4 w7 = *(const float4*)&s_w[7 * N_ + jj];
        PVROW(a0, w0) PVROW(a1, w1) PVROW(a2, w2) PVROW(a3, w3)
        PVROW(a4, w4) PVROW(a5, w5) PVROW(a6, w6) PVROW(a7, w7)
    }
#undef PVROW

    *(float4*)&s_part[jh * 1024 + 0 * 256 + dq * 4] = a0;
    *(float4*)&s_part[jh * 1024 + 1 * 256 + dq * 4] = a1;
    *(float4*)&s_part[jh * 1024 + 2 * 256 + dq * 4] = a2;
    *(float4*)&s_part[jh * 1024 + 3 * 256 + dq * 4] = a3;
    __syncthreads();
    if (t < 256) {
        const int r  = t >> 6;
        const int d4 = (t & 63) * 4;
        float4 s = make_float4(0.f,0.f,0.f,0.f);
        #pragma unroll
        for (int g = 0; g < 8; ++g) {
            const float4 p = *(const float4*)&s_part[g * 1024 + r * 256 + d4];
            s.x += p.x; s.y += p.y; s.z += p.z; s.w += p.w;
        }
        *(float4*)(out + ((size_t)(b * N_ + i0 + r)) * D_ + dh * 256 + d4) = s;
    }
    __syncthreads();
    *(float4*)&s_part[jh * 1024 + 0 * 256 + dq * 4] = a4;
    *(float4*)&s_part[jh * 1024 + 1 * 256 + dq * 4] = a5;
    *(float4*)&s_part[jh * 1024 + 2 * 256 + dq * 4] = a6;
    *(float4*)&s_part[jh * 1024 + 3 * 256 + dq * 4] = a7;
    __syncthreads();
    if (t < 256) {
        const int r  = t >> 6;
        const int d4 = (t & 63) * 4;
        float4 s = make_float4(0.f,0.f,0.f,0.f);
        #pragma unroll
        for (int g = 0; g < 8; ++g) {
            const float4 p = *(const float4*)&s_part[g * 1024 + r * 256 + d4];
            s.x += p.x; s.y += p.y; s.z += p.z; s.w += p.w;
        }
        *(float4*)(out + ((size_t)(b * N_ + i0 + 4 + r)) * D_ + dh * 256 + d4) = s;
    }
}

// ---------- Fallback (round-1 kernel) if ws too small ----------
__global__ __launch_bounds__(256, 2)
void manh_attn_legacy(const float* __restrict__ q,
                      const float* __restrict__ k,
                      const float* __restrict__ v,
                      float* __restrict__ out)
{
    __shared__ float s_mat[4][N_];
    const int t   = threadIdx.x;
    const int bid = blockIdx.x;
    const int b   = bid >> 6;
    const int i0  = (bid & 63) * 4;

    const float* __restrict__ krow  = k + ((size_t)(b * N_ + t)) * D_;
    const float* __restrict__ qbase = q + ((size_t)(b * N_ + i0)) * D_;

    float acc0 = 0.f, acc1 = 0.f, acc2 = 0.f, acc3 = 0.f;
    #pragma unroll 4
    for (int d = 0; d < D_; d += 4) {
        const float4 kv = *(const float4*)(krow + d);
        const float4 q0 = *(const float4*)(qbase + d);
        const float4 q1 = *(const float4*)(qbase + D_ + d);
        const float4 q2 = *(const float4*)(qbase + 2 * D_ + d);
        const float4 q3 = *(const float4*)(qbase + 3 * D_ + d);
        acc0 += (fabsf(q0.x - kv.x) + fabsf(q0.y - kv.y)) + (fabsf(q0.z - kv.z) + fabsf(q0.w - kv.w));
        acc1 += (fabsf(q1.x - kv.x) + fabsf(q1.y - kv.y)) + (fabsf(q1.z - kv.z) + fabsf(q1.w - kv.w));
        acc2 += (fabsf(q2.x - kv.x) + fabsf(q2.y - kv.y)) + (fabsf(q2.z - kv.z) + fabsf(q2.w - kv.w));
        acc3 += (fabsf(q3.x - kv.x) + fabsf(q3.y - kv.y)) + (fabsf(q3.z - kv.z) + fabsf(q3.w - kv.w));
    }
    s_mat[0][t] = -acc0; s_mat[1][t] = -acc1; s_mat[2][t] = -acc2; s_mat[3][t] = -acc3;
    __syncthreads();
    {
        const int w = t >> 6;
        const int l = t & 63;
        float v0 = s_mat[w][l], v1 = s_mat[w][l + 64], v2 = s_mat[w][l + 128], v3 = s_mat[w][l + 192];
        float m = fmaxf(fmaxf(v0, v1), fmaxf(v2, v3));
        #pragma unroll
        for (int off = 32; off; off >>= 1) m = fmaxf(m, __shfl_xor(m, off));
        const float c = 1.4426950408889634f;
        float e0 = exp2f((v0 - m) * c), e1 = exp2f((v1 - m) * c);
        float e2 = exp2f((v2 - m) * c), e3 = exp2f((v3 - m) * c);
        float s = (e0 + e1) + (e2 + e3);
        #pragma unroll
        for (int off = 32; off; off >>= 1) s += __shfl_xor(s, off);
        const float r = 1.0f / s;
        s_mat[w][l] = e0 * r; s_mat[w][l + 64] = e1 * r;
        s_mat[w][l + 128] = e2 * r; s_mat[w][l + 192] = e3 * r;
    }
    __syncthreads();
    const int ig = t >> 7;
    const int d0 = (t & 127) * 4;
    const float* __restrict__ vbase = v + ((size_t)b * N_) * D_ + d0;
    const float* __restrict__ wr0 = &s_mat[2 * ig][0];
    const float* __restrict__ wr1 = &s_mat[2 * ig + 1][0];
    float4 a0 = make_float4(0.f, 0.f, 0.f, 0.f);
    float4 a1 = make_float4(0.f, 0.f, 0.f, 0.f);
#define PV_STEP(W0, W1, VV)                                     \
    a0.x += (W0) * (VV).x; a0.y += (W0) * (VV).y;               \
    a0.z += (W0) * (VV).z; a0.w += (W0) * (VV).w;               \
    a1.x += (W1) * (VV).x; a1.y += (W1) * (VV).y;               \
    a1.z += (W1) * (VV).z; a1.w += (W1) * (VV).w;
    #pragma unroll 2
    for (int j = 0; j < N_; j += 4) {
        const float4 w0 = *(const float4*)(wr0 + j);
        const float4 w1 = *(const float4*)(wr1 + j);
        const float4 vv0 = *(const float4*)(vbase + (size_t)(j + 0) * D_);
        const float4 vv1 = *(const float4*)(vbase + (size_t)(j + 1) * D_);
        const float4 vv2 = *(const float4*)(vbase + (size_t)(j + 2) * D_);
        const float4 vv3 = *(const float4*)(vbase + (size_t)(j + 3) * D_);
        PV_STEP(w0.x, w1.x, vv0)
        PV_STEP(w0.y, w1.y, vv1)
        PV_STEP(w0.z, w1.z, vv2)
        PV_STEP(w0.w, w1.w, vv3)
    }
#undef PV_STEP
    float* op = out + ((size_t)(b * N_ + i0 + 2 * ig)) * D_ + d0;
    *(float4*)op        = a0;
    *(float4*)(op + D_) = a1;
}

extern "C" void kernel_launch(void* const* d_in, const int* in_sizes, int n_in,
                              void* d_out, int out_size, void* d_ws, size_t ws_size,
                              hipStream_t stream)
{
    const float* q = (const float*)d_in[0];
    const float* k = (const float*)d_in[1];
    const float* v = (const float*)d_in[2];
    float* out = (float*)d_out;

    const size_t kT_bytes = (size_t)B_ * N_ * D_ * sizeof(float);   // 4 MB
    const size_t S_bytes  = (size_t)B_ * N_ * N_ * sizeof(float);   // 2 MB
    if (ws_size >= kT_bytes + S_bytes) {
        float* kT = (float*)d_ws;
        float* S  = (float*)((char*)d_ws + kT_bytes);
        transpose_k <<<dim3(D_ / 32, N_ / 32, B_), dim3(32, 8), 0, stream>>>(k, kT);
        manh_scores7<<<dim3(1024), dim3(512), 0, stream>>>(q, kT, S);
        manh_sm_pv8 <<<dim3(512),  dim3(512), 0, stream>>>(S, v, out);
    } else {
        manh_attn_legacy<<<dim3(B_ * 64), dim3(256), 0, stream>>>(q, k, v, out);
    }
}

// Round 20
// 50.403 us; speedup vs baseline: 1.1396x; 1.1396x over previous
//
#include <hip/hip_runtime.h>

#define B_ 8
#define N_ 256
#define D_ 512

// async 16B global -> LDS. FULL-WAVE ONLY (exec-masked LDS-DMA corrupts LDS).
__device__ __forceinline__ void load_lds_16B(const float* g, float* l)
{
    __builtin_amdgcn_global_load_lds(
        (const __attribute__((address_space(1))) void*)g,
        (__attribute__((address_space(3))) void*)l, 16, 0, 0);
}

// ================= Kernel A: scores S[b][i][j] = -sum_d |q-k| =============
// grid 2048: b=bid&7, itile=(bid>>3)&31 -> 8 rows, jq=bid>>8 -> 32 j.
// 256 thr, 16 KB LDS -> 8 blocks/CU = 32 waves/CU (2x R15's occupancy).
// DMA-staged k (TA-cheap: 16 wave-DMDAs/block vs 5120 direct-load TA cost
// that capped scores6/7): chunk = 32 j x 64 d = 8 KB, double-buffered.
// Swizzle (re-derived, same family as R12/R16-verified):
//   slot [j*64 + gl*4 ..+3] holds k[jbase+j][c*64 + (gl^(j&15))*4 ..+3]
//   stage: thread t, DMA m: row j=(t>>4)+16m, src group=(t&15)^((t>>4)&15)
//   read : lane row j, want group gr -> gl = (gr^(j&15))&15  (round-trip ✓)
// Thread = (j = lane&31, rsub = lane>>5 -> rows rsub*4..+3); wave w owns
// contiguous d-groups 4w..4w+3. 4 scalar accs -> spill-proof.
__global__ __launch_bounds__(256, 8)
void manh_scores9(const float* __restrict__ q,
                  const float* __restrict__ k,
                  float* __restrict__ S)
{
    __shared__ __align__(16) float s_k[2][2048];   // 16 KB: 32j x 64d dbuf
    float* s_red = &s_k[0][0];                     // 4 KB alias after loop

    const int t     = threadIdx.x;
    const int b     = blockIdx.x & 7;          // batch -> XCD locality
    const int itile = (blockIdx.x >> 3) & 31;
    const int jq    = blockIdx.x >> 8;         // 0..7
    const int ibase = itile * 8;
    const int jbase = jq * 32;

    const float* __restrict__ kb = k + (size_t)b * N_ * D_;
    const float* __restrict__ qb = q + ((size_t)(b * N_ + ibase)) * D_;

    // --- staging sources (pre-swizzled global, linear LDS dest) ---
    const int dgsw = (t & 15) ^ ((t >> 4) & 15);
    const float* ksrc0 = kb + (size_t)(jbase + (t >> 4)) * D_ + dgsw * 4;
    const float* ksrc1 = ksrc0 + (size_t)16 * D_;

#define STAGE(cc, sb)                                           \
    {                                                           \
        load_lds_16B(ksrc0 + (cc) * 64, &s_k[sb][4 * t]);       \
        load_lds_16B(ksrc1 + (cc) * 64, &s_k[sb][4 * t + 1024]);\
    }

    STAGE(0, 0)
    __syncthreads();                   // chunk 0 resident

    const int lane = t & 63;
    const int w    = t >> 6;           // wave -> d-groups 4w..4w+3
    const int j    = lane & 31;
    const int rsub = lane >> 5;        // 0..1 -> rows rsub*4..+3
    const int swz  = j & 15;
    const float* __restrict__ qrow = qb + (size_t)(rsub * 4) * D_;

    float a0 = 0.f, a1 = 0.f, a2 = 0.f, a3 = 0.f;

    int buf = 0;
    for (int c = 0; c < 8; ++c) {
        if (c < 7) STAGE(c + 1, buf ^ 1)

        const float* kcb = &s_k[buf][j << 6];
        #pragma unroll
        for (int g2 = 0; g2 < 4; ++g2) {
            const int gr = 4 * w + g2;                     // wave-uniform
            const float4 k4 = *(const float4*)(kcb + (((gr ^ swz) & 15) << 2));
            const int doff = c * 64 + gr * 4;
            const float4 q0 = *(const float4*)(qrow + doff);
            const float4 q1 = *(const float4*)(qrow + D_ + doff);
            const float4 q2 = *(const float4*)(qrow + 2 * D_ + doff);
            const float4 q3 = *(const float4*)(qrow + 3 * D_ + doff);
            a0 += (fabsf(q0.x - k4.x) + fabsf(q0.y - k4.y)) +
                  (fabsf(q0.z - k4.z) + fabsf(q0.w - k4.w));
            a1 += (fabsf(q1.x - k4.x) + fabsf(q1.y - k4.y)) +
                  (fabsf(q1.z - k4.z) + fabsf(q1.w - k4.w));
            a2 += (fabsf(q2.x - k4.x) + fabsf(q2.y - k4.y)) +
                  (fabsf(q2.z - k4.z) + fabsf(q2.w - k4.w));
            a3 += (fabsf(q3.x - k4.x) + fabsf(q3.y - k4.y)) +
                  (fabsf(q3.z - k4.z) + fabsf(q3.w - k4.w));
        }

        __syncthreads();               // drains next-chunk DMA (issued early);
        buf ^= 1;                      // 8 co-resident blocks cover the skew
    }
#undef STAGE

    // ---- dump partials [w][rsub][R][j] (s_k[0] free: chunk 7 used s_k[1]) ----
    s_red[w * 256 + rsub * 128 + 0 * 32 + j] = a0;
    s_red[w * 256 + rsub * 128 + 1 * 32 + j] = a1;
    s_red[w * 256 + rsub * 128 + 2 * 32 + j] = a2;
    s_red[w * 256 + rsub * 128 + 3 * 32 + j] = a3;
    __syncthreads();

    // ---- reduce 4 wave-quarters -> S (one output per thread) ----
    {
        const int r  = t >> 5;                 // 0..7
        const int jj = t & 31;
        const int sl = (r >> 2) * 128 + (r & 3) * 32 + jj;
        const float sum = (s_red[0 * 256 + sl] + s_red[1 * 256 + sl]) +
                          (s_red[2 * 256 + sl] + s_red[3 * 256 + sl]);
        S[(size_t)b * N_ * N_ + (size_t)(ibase + r) * N_ + jbase + jj] = -sum;
    }
}

// ================= Kernel B: softmax(S) @ v, 8 rows/block (verified R13) ===
__global__ __launch_bounds__(512, 4)
void manh_sm_pv8(const float* __restrict__ S,
                 const float* __restrict__ v,
                 float* __restrict__ out)
{
    __shared__ __align__(16) float s_w[8 * N_];      // 8 KB
    __shared__ __align__(16) float s_part[8 * 1024]; // 32 KB

    const int t     = threadIdx.x;
    const int lane  = t & 63;
    const int w     = t >> 6;              // 0..7
    const int b     = blockIdx.x & 7;
    const int itile = (blockIdx.x >> 3) & 31;
    const int dh    = blockIdx.x >> 8;     // 0..1
    const int i0    = itile * 8;

    *(float4*)&s_w[4 * t] =
        *(const float4*)(S + (size_t)b * N_ * N_ + (size_t)i0 * N_ + 4 * t);
    __syncthreads();

    {
        float* row = &s_w[w * N_];
        float v0 = row[lane];
        float v1 = row[lane + 64];
        float v2 = row[lane + 128];
        float v3 = row[lane + 192];
        float m = fmaxf(fmaxf(v0, v1), fmaxf(v2, v3));
        #pragma unroll
        for (int off = 32; off; off >>= 1) m = fmaxf(m, __shfl_xor(m, off));
        const float cc = 1.4426950408889634f;
        float e0 = exp2f((v0 - m) * cc);
        float e1 = exp2f((v1 - m) * cc);
        float e2 = exp2f((v2 - m) * cc);
        float e3 = exp2f((v3 - m) * cc);
        float s = (e0 + e1) + (e2 + e3);
        #pragma unroll
        for (int off = 32; off; off >>= 1) s += __shfl_xor(s, off);
        const float r = 1.0f / s;
        row[lane]       = e0 * r;
        row[lane + 64]  = e1 * r;
        row[lane + 128] = e2 * r;
        row[lane + 192] = e3 * r;
    }
    __syncthreads();

    const int dq    = t & 63;
    const int jh    = t >> 6;              // == wave -> s_w reads wave-uniform
    const int dbase = dh * 256 + dq * 4;
    const float* __restrict__ vb = v + (size_t)b * N_ * D_ + dbase;

    float4 a0 = make_float4(0.f,0.f,0.f,0.f), a1 = a0, a2 = a0, a3 = a0;
    float4 a4 = a0, a5 = a0, a6 = a0, a7 = a0;

#define PVROW(A, W)                                                            \
    A.x += (W).x * vv0.x + (W).y * vv1.x + (W).z * vv2.x + (W).w * vv3.x;      \
    A.y += (W).x * vv0.y + (W).y * vv1.y + (W).z * vv2.y + (W).w * vv3.y;      \
    A.z += (W).x * vv0.z + (W).y * vv1.z + (W).z * vv2.z + (W).w * vv3.z;      \
    A.w += (W).x * vv0.w + (W).y * vv1.w + (W).z * vv2.w + (W).w * vv3.w;

    #pragma unroll 2
    for (int jo = 0; jo < 32; jo += 4) {
        const int jj = jh * 32 + jo;
        const float4 vv0 = *(const float4*)(vb + (size_t)(jj + 0) * D_);
        const float4 vv1 = *(const float4*)(vb + (size_t)(jj + 1) * D_);
        const float4 vv2 = *(const float4*)(vb + (size_t)(jj + 2) * D_);
        const float4 vv3 = *(const float4*)(vb + (size_t)(jj + 3) * D_);
        const float4 w0 = *(const float4*)&s_w[0 * N_ + jj];
        const float4 w1 = *(const float4*)&s_w[1 * N_ + jj];
        const float4 w2 = *(const float4*)&s_w[2 * N_ + jj];
        const float4 w3 = *(const float4*)&s_w[3 * N_ + jj];
        const float4 w4 = *(const float4*)&s_w[4 * N_ + jj];
        const float4 w5 = *(const float4*)&s_w[5 * N_ + jj];
        const float4 w6 = *(const float4*)&s_w[6 * N_ + jj];
        const float4 w7 = *(const float4*)&s_w[7 * N_ + jj];
        PVROW(a0, w0) PVROW(a1, w1) PVROW(a2, w2) PVROW(a3, w3)
        PVROW(a4, w4) PVROW(a5, w5) PVROW(a6, w6) PVROW(a7, w7)
    }
#undef PVROW

    *(float4*)&s_part[jh * 1024 + 0 * 256 + dq * 4] = a0;
    *(float4*)&s_part[jh * 1024 + 1 * 256 + dq * 4] = a1;
    *(float4*)&s_part[jh * 1024 + 2 * 256 + dq * 4] = a2;
    *(float4*)&s_part[jh * 1024 + 3 * 256 + dq * 4] = a3;
    __syncthreads();
    if (t < 256) {
        const int r  = t >> 6;
        const int d4 = (t & 63) * 4;
        float4 s = make_float4(0.f,0.f,0.f,0.f);
        #pragma unroll
        for (int g = 0; g < 8; ++g) {
            const float4 p = *(const float4*)&s_part[g * 1024 + r * 256 + d4];
            s.x += p.x; s.y += p.y; s.z += p.z; s.w += p.w;
        }
        *(float4*)(out + ((size_t)(b * N_ + i0 + r)) * D_ + dh * 256 + d4) = s;
    }
    __syncthreads();
    *(float4*)&s_part[jh * 1024 + 0 * 256 + dq * 4] = a4;
    *(float4*)&s_part[jh * 1024 + 1 * 256 + dq * 4] = a5;
    *(float4*)&s_part[jh * 1024 + 2 * 256 + dq * 4] = a6;
    *(float4*)&s_part[jh * 1024 + 3 * 256 + dq * 4] = a7;
    __syncthreads();
    if (t < 256) {
        const int r  = t >> 6;
        const int d4 = (t & 63) * 4;
        float4 s = make_float4(0.f,0.f,0.f,0.f);
        #pragma unroll
        for (int g = 0; g < 8; ++g) {
            const float4 p = *(const float4*)&s_part[g * 1024 + r * 256 + d4];
            s.x += p.x; s.y += p.y; s.z += p.z; s.w += p.w;
        }
        *(float4*)(out + ((size_t)(b * N_ + i0 + 4 + r)) * D_ + dh * 256 + d4) = s;
    }
}

// ---------- Fallback (round-1 kernel) if ws can't hold S (2 MB) ----------
__global__ __launch_bounds__(256, 2)
void manh_attn_legacy(const float* __restrict__ q,
                      const float* __restrict__ k,
                      const float* __restrict__ v,
                      float* __restrict__ out)
{
    __shared__ float s_mat[4][N_];
    const int t   = threadIdx.x;
    const int bid = blockIdx.x;
    const int b   = bid >> 6;
    const int i0  = (bid & 63) * 4;

    const float* __restrict__ krow  = k + ((size_t)(b * N_ + t)) * D_;
    const float* __restrict__ qbase = q + ((size_t)(b * N_ + i0)) * D_;

    float acc0 = 0.f, acc1 = 0.f, acc2 = 0.f, acc3 = 0.f;
    #pragma unroll 4
    for (int d = 0; d < D_; d += 4) {
        const float4 kv = *(const float4*)(krow + d);
        const float4 q0 = *(const float4*)(qbase + d);
        const float4 q1 = *(const float4*)(qbase + D_ + d);
        const float4 q2 = *(const float4*)(qbase + 2 * D_ + d);
        const float4 q3 = *(const float4*)(qbase + 3 * D_ + d);
        acc0 += (fabsf(q0.x - kv.x) + fabsf(q0.y - kv.y)) + (fabsf(q0.z - kv.z) + fabsf(q0.w - kv.w));
        acc1 += (fabsf(q1.x - kv.x) + fabsf(q1.y - kv.y)) + (fabsf(q1.z - kv.z) + fabsf(q1.w - kv.w));
        acc2 += (fabsf(q2.x - kv.x) + fabsf(q2.y - kv.y)) + (fabsf(q2.z - kv.z) + fabsf(q2.w - kv.w));
        acc3 += (fabsf(q3.x - kv.x) + fabsf(q3.y - kv.y)) + (fabsf(q3.z - kv.z) + fabsf(q3.w - kv.w));
    }
    s_mat[0][t] = -acc0; s_mat[1][t] = -acc1; s_mat[2][t] = -acc2; s_mat[3][t] = -acc3;
    __syncthreads();
    {
        const int w = t >> 6;
        const int l = t & 63;
        float v0 = s_mat[w][l], v1 = s_mat[w][l + 64], v2 = s_mat[w][l + 128], v3 = s_mat[w][l + 192];
        float m = fmaxf(fmaxf(v0, v1), fmaxf(v2, v3));
        #pragma unroll
        for (int off = 32; off; off >>= 1) m = fmaxf(m, __shfl_xor(m, off));
        const float c = 1.4426950408889634f;
        float e0 = exp2f((v0 - m) * c), e1 = exp2f((v1 - m) * c);
        float e2 = exp2f((v2 - m) * c), e3 = exp2f((v3 - m) * c);
        float s = (e0 + e1) + (e2 + e3);
        #pragma unroll
        for (int off = 32; off; off >>= 1) s += __shfl_xor(s, off);
        const float r = 1.0f / s;
        s_mat[w][l] = e0 * r; s_mat[w][l + 64] = e1 * r;
        s_mat[w][l + 128] = e2 * r; s_mat[w][l + 192] = e3 * r;
    }
    __syncthreads();
    const int ig = t >> 7;
    const int d0 = (t & 127) * 4;
    const float* __restrict__ vbase = v + ((size_t)b * N_) * D_ + d0;
    const float* __restrict__ wr0 = &s_mat[2 * ig][0];
    const float* __restrict__ wr1 = &s_mat[2 * ig + 1][0];
    float4 a0 = make_float4(0.f, 0.f, 0.f, 0.f);
    float4 a1 = make_float4(0.f, 0.f, 0.f, 0.f);
#define PV_STEP(W0, W1, VV)                                     \
    a0.x += (W0) * (VV).x; a0.y += (W0) * (VV).y;               \
    a0.z += (W0) * (VV).z; a0.w += (W0) * (VV).w;               \
    a1.x += (W1) * (VV).x; a1.y += (W1) * (VV).y;               \
    a1.z += (W1) * (VV).z; a1.w += (W1) * (VV).w;
    #pragma unroll 2
    for (int j = 0; j < N_; j += 4) {
        const float4 w0 = *(const float4*)(wr0 + j);
        const float4 w1 = *(const float4*)(wr1 + j);
        const float4 vv0 = *(const float4*)(vbase + (size_t)(j + 0) * D_);
        const float4 vv1 = *(const float4*)(vbase + (size_t)(j + 1) * D_);
        const float4 vv2 = *(const float4*)(vbase + (size_t)(j + 2) * D_);
        const float4 vv3 = *(const float4*)(vbase + (size_t)(j + 3) * D_);
        PV_STEP(w0.x, w1.x, vv0)
        PV_STEP(w0.y, w1.y, vv1)
        PV_STEP(w0.z, w1.z, vv2)
        PV_STEP(w0.w, w1.w, vv3)
    }
#undef PV_STEP
    float* op = out + ((size_t)(b * N_ + i0 + 2 * ig)) * D_ + d0;
    *(float4*)op        = a0;
    *(float4*)(op + D_) = a1;
}

extern "C" void kernel_launch(void* const* d_in, const int* in_sizes, int n_in,
                              void* d_out, int out_size, void* d_ws, size_t ws_size,
                              hipStream_t stream)
{
    const float* q = (const float*)d_in[0];
    const float* k = (const float*)d_in[1];
    const float* v = (const float*)d_in[2];
    float* out = (float*)d_out;

    const size_t S_bytes = (size_t)B_ * N_ * N_ * sizeof(float);   // 2 MB
    if (ws_size >= S_bytes) {
        float* S = (float*)d_ws;
        manh_scores9<<<dim3(2048), dim3(256), 0, stream>>>(q, k, S);
        manh_sm_pv8 <<<dim3(512),  dim3(512), 0, stream>>>(S, v, out);
    } else {
        manh_attn_legacy<<<dim3(B_ * 64), dim3(256), 0, stream>>>(q, k, v, out);
    }
}